// Round 1
// baseline (233.412 us; speedup 1.0000x reference)
//
#include <hip/hip_runtime.h>

// WaveNet gated residual block, MI355X bf16-MFMA implementation (v1).
// B=8, Cin=128, T=16000, dilation=4, K=3 causal; cond 80ch -> 2R=256 preact;
// gate -> z(128ch); out = Wout@z (128), skip = Wskip@z (256).
//
// Pipeline:
//   pack_weights : f32 weights -> bf16 packed [M][K] rows (ws)
//   transpose_bt : f32 [B][C][T] -> bf16 [B][T][Cp] (d_out used as scratch;
//                  k2 rewrites every byte of d_out afterwards, same stream)
//   k1_gate      : x = Wconv*in(3 taps) + Wcond*cond + bias; gate; z -> ws (bf16)
//   k2_outskip   : [out;skip] = [Wout;Wskip] @ z + bias -> d_out (f32)
//
// ws usage: (98304+24576+49152+16384000)*2 = 33.1 MB.

#define NB 8
#define NT 16000
#define CIN 128
#define CCOND 80
#define CCP 96
#define TT 64

typedef __attribute__((ext_vector_type(8))) __bf16 bf16x8;
typedef __attribute__((ext_vector_type(4))) float f32x4;

__device__ __forceinline__ unsigned short f2bf(float f) {
  unsigned int u = __float_as_uint(f);
  return (unsigned short)((u + 0x7fffu + ((u >> 16) & 1u)) >> 16);  // RNE
}
__device__ __forceinline__ bf16x8 ldb8(const unsigned short* p) {
  return *reinterpret_cast<const bf16x8*>(p);
}

// ---- pack weights to bf16 [M][K] ----
__global__ void pack_weights(const float* __restrict__ wc, const float* __restrict__ wcd,
                             const float* __restrict__ wo, const float* __restrict__ wsk,
                             unsigned short* __restrict__ wpc,   // [256][384] k=tap*128+c
                             unsigned short* __restrict__ wpcd,  // [256][96]  zero-pad k>=80
                             unsigned short* __restrict__ wp2)   // [384][128] rows 0-127 Wout, 128-383 Wskip
{
  int idx = blockIdx.x * 256 + threadIdx.x;
  if (idx < 98304) {
    int o = idx / 384, k = idx - o * 384;
    int tap = k >> 7, c = k & 127;
    wpc[idx] = f2bf(wc[(o * 128 + c) * 3 + tap]);
  } else if (idx < 122880) {
    int i = idx - 98304;
    int o = i / 96, k = i - o * 96;
    wpcd[i] = f2bf(k < CCOND ? wcd[o * CCOND + k] : 0.f);
  } else if (idx < 172032) {
    int i = idx - 122880;
    int m = i >> 7, k = i & 127;
    wp2[i] = f2bf(m < 128 ? wo[m * 128 + k] : wsk[(m - 128) * 128 + k]);
  }
}

// ---- f32 [B][C][NT] -> bf16 [B][NT][Cp], zero pad c in [C,Cp) ----
__global__ void transpose_bt(const float* __restrict__ in, unsigned short* __restrict__ outT,
                             int C, int Cp)
{
  __shared__ float tile[32][33];
  int t0 = blockIdx.x * 32, c0 = blockIdx.y * 32, b = blockIdx.z;
  int tx = threadIdx.x & 31, ty = threadIdx.x >> 5;  // ty 0..7
  #pragma unroll
  for (int i = 0; i < 4; ++i) {
    int c = c0 + ty + i * 8;
    float v = 0.f;
    if (c < C) v = in[((size_t)b * C + c) * NT + t0 + tx];
    tile[ty + i * 8][tx] = v;           // tile[c_local][t_local]
  }
  __syncthreads();
  #pragma unroll
  for (int i = 0; i < 4; ++i) {
    int t = ty + i * 8;
    outT[((size_t)b * NT + t0 + t) * Cp + c0 + tx] = f2bf(tile[tx][t]);
  }
}

// ---- k1: conv + cond GEMM (M=256, N=64, K=480) + bias + gate -> z bf16 ----
__global__ __launch_bounds__(256) void k1_gate(
    const unsigned short* __restrict__ wpc, const unsigned short* __restrict__ wpcd,
    const unsigned short* __restrict__ inT, const unsigned short* __restrict__ cdT,
    const float* __restrict__ bconv, unsigned short* __restrict__ zb)
{
  __shared__ float xbuf[256][69];       // pad 69: store 2-way-ish, reads ~free
  int b = blockIdx.y;
  int t0 = blockIdx.x * TT;
  int tid = threadIdx.x;
  int lane = tid & 63, w = tid >> 6;
  int l15 = lane & 15, g = lane >> 4;
  int mbase = w * 64;                   // wave owns 64 output channels

  f32x4 acc[4][4] = {};

  // conv taps: x(t) += sum_c W[o][c][tap] * in[c][t - 8 + 4*tap]
  #pragma unroll
  for (int tap = 0; tap < 3; ++tap) {
    #pragma unroll
    for (int kc = 0; kc < 4; ++kc) {
      int k0 = kc * 32 + g * 8;
      bf16x8 afr[4];
      #pragma unroll
      for (int mf = 0; mf < 4; ++mf)
        afr[mf] = ldb8(&wpc[(size_t)(mbase + mf * 16 + l15) * 384 + tap * 128 + k0]);
      bf16x8 bfr[4];
      #pragma unroll
      for (int nf = 0; nf < 4; ++nf) {
        int t = t0 + nf * 16 + l15 - 8 + tap * 4;
        bf16x8 v = {};
        if (t >= 0) v = ldb8(&inT[((size_t)b * NT + t) * CIN + k0]);
        bfr[nf] = v;
      }
      #pragma unroll
      for (int mf = 0; mf < 4; ++mf)
        #pragma unroll
        for (int nf = 0; nf < 4; ++nf)
          acc[mf][nf] = __builtin_amdgcn_mfma_f32_16x16x32_bf16(afr[mf], bfr[nf], acc[mf][nf], 0, 0, 0);
    }
  }
  // cond (K padded 80->96)
  #pragma unroll
  for (int kc = 0; kc < 3; ++kc) {
    int k0 = kc * 32 + g * 8;
    bf16x8 afr[4];
    #pragma unroll
    for (int mf = 0; mf < 4; ++mf)
      afr[mf] = ldb8(&wpcd[(size_t)(mbase + mf * 16 + l15) * CCP + k0]);
    bf16x8 bfr[4];
    #pragma unroll
    for (int nf = 0; nf < 4; ++nf) {
      int t = t0 + nf * 16 + l15;
      bfr[nf] = ldb8(&cdT[((size_t)b * NT + t) * CCP + k0]);
    }
    #pragma unroll
    for (int mf = 0; mf < 4; ++mf)
      #pragma unroll
      for (int nf = 0; nf < 4; ++nf)
        acc[mf][nf] = __builtin_amdgcn_mfma_f32_16x16x32_bf16(afr[mf], bfr[nf], acc[mf][nf], 0, 0, 0);
  }

  // bias + stash pre-activation x into LDS (D layout: col=lane&15, row=g*4+j)
  float bia[4][4];
  #pragma unroll
  for (int mf = 0; mf < 4; ++mf)
    #pragma unroll
    for (int j = 0; j < 4; ++j)
      bia[mf][j] = bconv[mbase + mf * 16 + g * 4 + j];
  #pragma unroll
  for (int mf = 0; mf < 4; ++mf)
    #pragma unroll
    for (int nf = 0; nf < 4; ++nf)
      #pragma unroll
      for (int j = 0; j < 4; ++j)
        xbuf[mbase + mf * 16 + g * 4 + j][nf * 16 + l15] = acc[mf][nf][j] + bia[mf][j];
  __syncthreads();

  // gate: z[c][n] = tanh(x[c])*sigmoid(x[c+128]); write z[B][T][128] bf16 (paired u32)
  #pragma unroll
  for (int i = 0; i < 16; ++i) {
    int idx = i * 256 + tid;
    int c = (idx & 63) * 2;
    int n = idx >> 6;
    float a0 = xbuf[c][n], a1 = xbuf[c + 1][n];
    float s0 = xbuf[c + 128][n], s1 = xbuf[c + 129][n];
    float z0 = (1.f - 2.f / (1.f + __expf(2.f * a0))) * (1.f / (1.f + __expf(-s0)));
    float z1 = (1.f - 2.f / (1.f + __expf(2.f * a1))) * (1.f / (1.f + __expf(-s1)));
    unsigned int pk = (unsigned int)f2bf(z0) | ((unsigned int)f2bf(z1) << 16);
    *reinterpret_cast<unsigned int*>(&zb[((size_t)b * NT + t0 + n) * CIN + c]) = pk;
  }
}

// ---- k2: [out;skip] = [Wout;Wskip](384x128) @ z + bias ----
__global__ __launch_bounds__(256) void k2_outskip(
    const unsigned short* __restrict__ wp2, const unsigned short* __restrict__ zb,
    const float* __restrict__ bout, const float* __restrict__ bskip,
    float* __restrict__ out)
{
  int b = blockIdx.y, t0 = blockIdx.x * TT, tid = threadIdx.x;
  int lane = tid & 63, w = tid >> 6, l15 = lane & 15, g = lane >> 4;
  int mbase = w * 96;                   // wave owns 96 of 384 stacked rows
  f32x4 acc[6][4] = {};
  #pragma unroll
  for (int kc = 0; kc < 4; ++kc) {
    int k0 = kc * 32 + g * 8;
    bf16x8 bfr[4];
    #pragma unroll
    for (int nf = 0; nf < 4; ++nf)
      bfr[nf] = ldb8(&zb[((size_t)b * NT + t0 + nf * 16 + l15) * CIN + k0]);
    #pragma unroll
    for (int mf = 0; mf < 6; ++mf) {
      bf16x8 afr = ldb8(&wp2[(size_t)(mbase + mf * 16 + l15) * 128 + k0]);
      #pragma unroll
      for (int nf = 0; nf < 4; ++nf)
        acc[mf][nf] = __builtin_amdgcn_mfma_f32_16x16x32_bf16(afr, bfr[nf], acc[mf][nf], 0, 0, 0);
    }
  }
  float* skipp = out + (size_t)NB * 128 * NT;
  #pragma unroll
  for (int mf = 0; mf < 6; ++mf) {
    int mrow = mbase + mf * 16 + g * 4;
    #pragma unroll
    for (int j = 0; j < 4; ++j) {
      int m = mrow + j;
      float bv;
      float* basep;
      if (m < 128) { bv = bout[m];        basep = out   + ((size_t)b * 128 + m) * NT; }
      else         { bv = bskip[m - 128]; basep = skipp + ((size_t)b * 256 + (m - 128)) * NT; }
      #pragma unroll
      for (int nf = 0; nf < 4; ++nf)
        basep[t0 + nf * 16 + l15] = acc[mf][nf][j] + bv;
    }
  }
}

extern "C" void kernel_launch(void* const* d_in, const int* in_sizes, int n_in,
                              void* d_out, int out_size, void* d_ws, size_t ws_size,
                              hipStream_t stream)
{
  const float* input = (const float*)d_in[0];
  const float* cond  = (const float*)d_in[1];
  const float* wconv = (const float*)d_in[2];
  const float* bconv = (const float*)d_in[3];
  const float* wcond = (const float*)d_in[4];
  const float* wout  = (const float*)d_in[5];
  const float* boutp = (const float*)d_in[6];
  const float* wskip = (const float*)d_in[7];
  const float* bskip = (const float*)d_in[8];
  float* out = (float*)d_out;

  // ws layout (bf16 elems): weights then z
  unsigned short* wpc  = (unsigned short*)d_ws;     //  98304
  unsigned short* wpcd = wpc + 98304;               //  24576
  unsigned short* wp2  = wpcd + 24576;              //  49152
  unsigned short* zb   = wp2 + 49152;               //  16,384,000
  // transposed activations live in d_out scratch (k2 rewrites all of d_out)
  unsigned short* inT  = (unsigned short*)d_out;    //  16,384,000 elems (32.77 MB)
  unsigned short* cdT  = inT + (size_t)16384000;    //  12,288,000 elems (24.58 MB)

  pack_weights<<<672, 256, 0, stream>>>(wconv, wcond, wout, wskip, wpc, wpcd, wp2);
  transpose_bt<<<dim3(500, 4, NB), 256, 0, stream>>>(input, inT, 128, 128);
  transpose_bt<<<dim3(500, 3, NB), 256, 0, stream>>>(cond, cdT, 80, CCP);
  k1_gate<<<dim3(250, NB), 256, 0, stream>>>(wpc, wpcd, inT, cdT, bconv, zb);
  k2_outskip<<<dim3(250, NB), 256, 0, stream>>>(wp2, zb, boutp, bskip, out);
}